// Round 1
// baseline (1361.745 us; speedup 1.0000x reference)
//
#include <hip/hip_runtime.h>
#include <math.h>

#define Bn   8
#define Cn   256
#define HWn  4096
#define FB   (Cn * HWn)      // 1048576 elems per batch-field
#define NTOT (Bn * FB)       // 8388608 elems per field
#define TEND 1.0
#define EPSK 1e-12f
#define NT   64              // apply N-tile (positions)
#define RS   56              // Pb LDS row stride (bf16) — 112B: 2-way bank alias only

typedef float f32x4 __attribute__((ext_vector_type(4)));
typedef short bf16x8 __attribute__((ext_vector_type(8)));

__device__ inline float b2f(unsigned int u) {
    return __uint_as_float(u << 16);
}
__device__ inline unsigned short f2b(float f) {  // RNE
    unsigned u = __float_as_uint(f);
    unsigned r = u + 0x7FFFu + ((u >> 16) & 1u);
    return (unsigned short)(r >> 16);
}

// acc layout (floats, 8 batches each):
//   D[k][j] at acc[(k*8+j)*8 + b];  Nsq[j] at acc[512 + j*8 + b];  coords at acc+576

__global__ void init_kernel(float* __restrict__ p) {
    for (int i = threadIdx.x; i < 1024; i += 256) p[i] = 0.0f;
}

// ---- split W into bf16 hi/lo in MFMA-A staged layout ----
// layout: Whs[((kc*16+mt)*64+lane)*8+j] = bf16 of W[mt*16+(lane&15)][kc*32+(lane>>4)*8+j]
__global__ void wsplit_kernel(const float* __restrict__ W,
                              unsigned short* __restrict__ Whs,
                              unsigned short* __restrict__ Wls) {
    int kc = blockIdx.x, mt = blockIdx.y, l = threadIdx.x;
    int m = mt * 16 + (l & 15);
    int k0 = kc * 32 + (l >> 4) * 8;
#pragma unroll
    for (int j = 0; j < 8; ++j) {
        float wv = W[m * 256 + k0 + j];
        unsigned short h = f2b(wv);
        unsigned short lo = f2b(wv - b2f(h));
        int idx = ((kc * 16 + mt) * 64 + l) * 8 + j;
        Whs[idx] = h; Wls[idx] = lo;
    }
}

// ================= fused Krylov step K (K = 0..7) =================
// phase 1 : x = U_K = w - sum_{j<K} cj_j * basis_j   (basis_0 = v fp32, else Q bf16)
//           -> write Q_{K-1} field (bf16), Nsq[K] atomic, t[s] = colsum(s0*x) (block-local)
//           (K==0: x = v fp32, Nsq[0] = ||v||^2)
// phase 2 : w' = W @ (s0 .* (x - t))  via split-bf16 MFMA.
//           Z eliminated: W@(s0.x) - (W@s0).t == W@(s0.*(x - t.1)).
//           A-fragments read straight from global (L2-hot, zero intra-block reuse).
// epilogue: write w' in place; dots D[K][j] = <basis_j, w'>, j=0..K (atomics)
template <int K>
__global__ __launch_bounds__(256, 3) void step_kernel(
        const float* __restrict__ v, const float* __restrict__ s0,
        const unsigned short* __restrict__ Whs, const unsigned short* __restrict__ Wls,
        unsigned short* __restrict__ Qb, float* __restrict__ acc,
        float* __restrict__ w) {
    __shared__ short Ph[NT * RS], Pl[NT * RS];   // 7 KB each
    __shared__ float tred[16 * 64];              // 4 KB
    __shared__ float ts[NT];
    __shared__ float nred[4];
    __shared__ float dred[4][8];
    const int tid = threadIdx.x;
    const int b = blockIdx.y;
    const int sbase = blockIdx.x * NT;
    const size_t boff = (size_t)b * FB;
    const int lane = tid & 63, wvi = tid >> 6;
    const int mbase = wvi * 64;
    const int cg = tid >> 4;         // 0..15
    const int pos = (tid & 15) * 4;  // 0..60

    // ---- CGS coefficients from previous step's dots ----
    float cj[K > 0 ? K : 1];
    if (K > 0) {
        float mm[K > 0 ? K : 1];
        mm[0] = sqrtf(acc[512 + b]);
#pragma unroll
        for (int j = 1; j < K; ++j) mm[j] = sqrtf(acc[512 + j * 8 + b]) + EPSK * mm[j - 1];
#pragma unroll
        for (int j = 0; j < K; ++j)
            cj[j] = acc[((K - 1) * 8 + j) * 8 + b] / (mm[j] * mm[j]);
    }
    unsigned short* QK = Qb + (size_t)(K > 0 ? K - 1 : 0) * NTOT;

    // ---- phase 1 ----
    float tp[4] = {0.f, 0.f, 0.f, 0.f};
    float np = 0.f;
#pragma unroll 4
    for (int cc = 0; cc < 16; ++cc) {
        int c = cc * 16 + cg;
        size_t off = boff + (size_t)c * HWn + sbase + pos;
        float4 sv = *(const float4*)(s0 + off);
        float se[4] = {sv.x, sv.y, sv.z, sv.w};
        if (K == 0) {
            float4 xv = *(const float4*)(v + off);
            float xe[4] = {xv.x, xv.y, xv.z, xv.w};
#pragma unroll
            for (int i = 0; i < 4; ++i) {
                np = fmaf(xe[i], xe[i], np);
                tp[i] = fmaf(xe[i], se[i], tp[i]);
            }
        } else {
            float4 wv4 = *(const float4*)(w + off);
            float4 vv4 = *(const float4*)(v + off);
            float xe[4];
            xe[0] = fmaf(-cj[0], vv4.x, wv4.x);
            xe[1] = fmaf(-cj[0], vv4.y, wv4.y);
            xe[2] = fmaf(-cj[0], vv4.z, wv4.z);
            xe[3] = fmaf(-cj[0], vv4.w, wv4.w);
#pragma unroll
            for (int j = 1; j < K; ++j) {
                ushort4 u = *(const ushort4*)(Qb + (size_t)(j - 1) * NTOT + off);
                xe[0] = fmaf(-cj[j], b2f(u.x), xe[0]);
                xe[1] = fmaf(-cj[j], b2f(u.y), xe[1]);
                xe[2] = fmaf(-cj[j], b2f(u.z), xe[2]);
                xe[3] = fmaf(-cj[j], b2f(u.w), xe[3]);
            }
            unsigned int h0 = f2b(xe[0]), h1 = f2b(xe[1]);
            unsigned int h2 = f2b(xe[2]), h3 = f2b(xe[3]);
            ushort4 o;
            o.x = (unsigned short)h0; o.y = (unsigned short)h1;
            o.z = (unsigned short)h2; o.w = (unsigned short)h3;
            *(ushort4*)(QK + off) = o;
            float xr[4] = {b2f(h0), b2f(h1), b2f(h2), b2f(h3)};
#pragma unroll
            for (int i = 0; i < 4; ++i) {
                np = fmaf(xr[i], xr[i], np);
                tp[i] = fmaf(xr[i], se[i], tp[i]);
            }
        }
    }
    for (int off2 = 32; off2 > 0; off2 >>= 1) np += __shfl_down(np, off2);
    if (lane == 0) nred[wvi] = np;
#pragma unroll
    for (int i = 0; i < 4; ++i) tred[cg * 64 + pos + i] = tp[i];
    __syncthreads();
    if (tid < 64) {
        float s = 0.f;
#pragma unroll
        for (int g = 0; g < 16; ++g) s += tred[g * 64 + tid];
        ts[tid] = s;
    }
    if (tid == 0)
        atomicAdd(&acc[512 + K * 8 + b], nred[0] + nred[1] + nred[2] + nred[3]);
    __syncthreads();

    // ---- phase 2: MFMA over 8 k-chunks ----
    f32x4 ac[4][4];
#pragma unroll
    for (int i = 0; i < 4; ++i)
#pragma unroll
        for (int j = 0; j < 4; ++j) ac[i][j] = (f32x4){0.f, 0.f, 0.f, 0.f};

    for (int kc = 0; kc < 8; ++kc) {
        __syncthreads();  // protect Ph/Pl from previous chunk's reads
#pragma unroll
        for (int ci = 0; ci < 2; ++ci) {
            int cl = ci * 16 + cg;          // 0..31
            int c = kc * 32 + cl;
            size_t off = boff + (size_t)c * HWn + sbase + pos;
            float4 sv = *(const float4*)(s0 + off);
            float se[4] = {sv.x, sv.y, sv.z, sv.w};
            float xr[4];
            if (K == 0) {
                float4 xv = *(const float4*)(v + off);
                xr[0] = xv.x; xr[1] = xv.y; xr[2] = xv.z; xr[3] = xv.w;
            } else {
                ushort4 u = *(const ushort4*)(QK + off);   // just written, L1/L2-hot
                xr[0] = b2f(u.x); xr[1] = b2f(u.y); xr[2] = b2f(u.z); xr[3] = b2f(u.w);
            }
#pragma unroll
            for (int i = 0; i < 4; ++i) {
                float p = se[i] * (xr[i] - ts[pos + i]);
                unsigned short h = f2b(p);
                unsigned short l = f2b(p - b2f(h));
                Ph[(pos + i) * RS + cl] = (short)h;
                Pl[(pos + i) * RS + cl] = (short)l;
            }
        }
        __syncthreads();
        bf16x8 ah[4], al[4], bh[4], bl[4];
#pragma unroll
        for (int rt = 0; rt < 4; ++rt) {
            int mt = (mbase >> 4) + rt;
            ah[rt] = *(const bf16x8*)(Whs + (size_t)kc * 8192 + (mt * 64 + lane) * 8);
            al[rt] = *(const bf16x8*)(Wls + (size_t)kc * 8192 + (mt * 64 + lane) * 8);
        }
#pragma unroll
        for (int ct = 0; ct < 4; ++ct) {
            int n = ct * 16 + (lane & 15);
            int k8 = (lane >> 4) * 8;
            bh[ct] = *(bf16x8*)(Ph + n * RS + k8);
            bl[ct] = *(bf16x8*)(Pl + n * RS + k8);
        }
#pragma unroll
        for (int rt = 0; rt < 4; ++rt)
#pragma unroll
            for (int ct = 0; ct < 4; ++ct) {
                ac[rt][ct] = __builtin_amdgcn_mfma_f32_16x16x32_bf16(ah[rt], bh[ct], ac[rt][ct], 0, 0, 0);
                ac[rt][ct] = __builtin_amdgcn_mfma_f32_16x16x32_bf16(ah[rt], bl[ct], ac[rt][ct], 0, 0, 0);
                ac[rt][ct] = __builtin_amdgcn_mfma_f32_16x16x32_bf16(al[rt], bh[ct], ac[rt][ct], 0, 0, 0);
            }
    }

    // ---- epilogue: write w' in place + dots D[K][j] = <basis_j, w'> ----
    // C/D layout: col=lane&15, row=(lane>>4)*4+reg
    float dp[K + 1];
#pragma unroll
    for (int j = 0; j <= K; ++j) dp[j] = 0.f;
#pragma unroll
    for (int rt = 0; rt < 4; ++rt)
#pragma unroll
        for (int ct = 0; ct < 4; ++ct) {
            int sl = ct * 16 + (lane & 15);
            int sg = sbase + sl;
            int r0 = mbase + rt * 16 + (lane >> 4) * 4;
#pragma unroll
            for (int reg = 0; reg < 4; ++reg) {
                size_t idx = boff + (size_t)(r0 + reg) * HWn + sg;
                float g = ac[rt][ct][reg];
                w[idx] = g;
                dp[0] = fmaf(g, v[idx], dp[0]);
#pragma unroll
                for (int j = 1; j <= K; ++j)
                    dp[j] = fmaf(g, b2f(Qb[(size_t)(j - 1) * NTOT + idx]), dp[j]);
            }
        }
#pragma unroll
    for (int j = 0; j <= K; ++j) {
        float q = dp[j];
        for (int off2 = 32; off2 > 0; off2 >>= 1) q += __shfl_down(q, off2);
        if (lane == 0) dred[wvi][j] = q;
    }
    __syncthreads();
    if (tid <= K)
        atomicAdd(&acc[(K * 8 + tid) * 8 + b],
                  dred[0][tid] + dred[1][tid] + dred[2][tid] + dred[3][tid]);
}

// ---------------- expm of 9x9 per batch (fp64); emits combine coeffs ----------
__global__ __launch_bounds__(128) void expm_kernel(const float* __restrict__ acc,
                                                   float* __restrict__ coordsOut) {
    __shared__ double Am[81], Pm[81], Tm[81];
    __shared__ double ssc;
    __shared__ int sn;
    const int b = blockIdx.x;
    const int t = threadIdx.x;
    const int r = t / 9, c = t % 9;
    double m[8];
    m[0] = sqrt((double)acc[512 + b]);
    for (int j = 1; j < 8; ++j) m[j] = sqrt((double)acc[512 + j * 8 + b]) + 1e-12 * m[j - 1];
    if (t < 81) {
        double val = 0.0;
        if (r < 8 && c < 8) {
            if (r <= c) val = TEND * (double)acc[(c * 8 + r) * 8 + b] / (m[r] * m[c]);
            else if (r == c + 1) val = TEND * sqrt((double)acc[512 + r * 8 + b]) / m[c];
        }
        if (r == 0 && c == 8) val = TEND;
        Am[t] = val;
    }
    __syncthreads();
    if (t == 0) {
        double mx = 0.0;
        for (int rr = 0; rr < 9; ++rr) {
            double s = 0.0;
            for (int cc = 0; cc < 9; ++cc) s += fabs(Am[rr * 9 + cc]);
            if (s > mx) mx = s;
        }
        int n = 0;
        while (mx > 0.25 && n < 48) { mx *= 0.5; ++n; }
        double sc = 1.0;
        for (int ii = 0; ii < n; ++ii) sc *= 0.5;
        sn = n; ssc = sc;
    }
    __syncthreads();
    if (t < 81) Am[t] *= ssc;
    __syncthreads();
    if (t < 81) Pm[t] = (r == c) ? 1.0 : 0.0;
    __syncthreads();
    for (int i = 20; i >= 1; --i) {
        if (t < 81) {
            double s = 0.0;
            for (int k = 0; k < 9; ++k) s += Am[r * 9 + k] * Pm[k * 9 + c];
            Tm[t] = ((r == c) ? 1.0 : 0.0) + s / (double)i;
        }
        __syncthreads();
        if (t < 81) Pm[t] = Tm[t];
        __syncthreads();
    }
    int n = sn;
    for (int q = 0; q < n; ++q) {
        if (t < 81) {
            double s = 0.0;
            for (int k = 0; k < 9; ++k) s += Pm[r * 9 + k] * Pm[k * 9 + c];
            Tm[t] = s;
        }
        __syncthreads();
        if (t < 81) Pm[t] = Tm[t];
        __syncthreads();
    }
    if (t < 8) coordsOut[b * 8 + t] = (float)(Pm[t * 9 + 8] * m[0] / m[t]);
}

__device__ inline void unp8(uint4 u, float* f) {
    f[0] = b2f(u.x & 0xFFFFu); f[1] = b2f(u.x >> 16);
    f[2] = b2f(u.y & 0xFFFFu); f[3] = b2f(u.y >> 16);
    f[4] = b2f(u.z & 0xFFFFu); f[5] = b2f(u.z >> 16);
    f[6] = b2f(u.w & 0xFFFFu); f[7] = b2f(u.w >> 16);
}

// ------ out = coeff_0*v + sum_{j=1..7} coeff_j * U_j (bf16) ------
__global__ __launch_bounds__(256) void combine_kernel(const unsigned short* __restrict__ Qb,
                                                      const float* __restrict__ v,
                                                      const float* __restrict__ coords,
                                                      float* __restrict__ out) {
    int b = blockIdx.y;
    const size_t boff = (size_t)b * FB;
    float cf[8];
#pragma unroll
    for (int j = 0; j < 8; ++j) cf[j] = coords[b * 8 + j];
    const float4* vv = (const float4*)(v + boff);
    const uint4* uv[8];
#pragma unroll
    for (int j = 1; j < 8; ++j)
        uv[j] = (const uint4*)(Qb + (size_t)(j - 1) * NTOT + boff);
    int i = blockIdx.x * 256 + threadIdx.x;
    float4* ov = (float4*)(out + boff);
#pragma unroll
    for (int r = 0; r < 2; ++r) {
        int idx = i + r * 65536;
        float4 v0 = vv[2 * idx], v1 = vv[2 * idx + 1];
        float a[8] = {cf[0] * v0.x, cf[0] * v0.y, cf[0] * v0.z, cf[0] * v0.w,
                      cf[0] * v1.x, cf[0] * v1.y, cf[0] * v1.z, cf[0] * v1.w};
#pragma unroll
        for (int j = 1; j < 8; ++j) {
            uint4 u = uv[j][idx];
            float ue[8]; unp8(u, ue);
#pragma unroll
            for (int e = 0; e < 8; ++e) a[e] = fmaf(cf[j], ue[e], a[e]);
        }
        float4 o0 = {a[0], a[1], a[2], a[3]};
        float4 o1 = {a[4], a[5], a[6], a[7]};
        ov[2 * idx] = o0; ov[2 * idx + 1] = o1;
    }
}

extern "C" void kernel_launch(void* const* d_in, const int* in_sizes, int n_in,
                              void* d_out, int out_size, void* d_ws, size_t ws_size,
                              hipStream_t stream) {
    const float* s0 = (const float*)d_in[0];
    const float* v  = (const float*)d_in[1];
    const float* W  = (const float*)d_in[2];
    float* out = (float*)d_out;

    // ws (floats): [acc 576 | coords 64 | pad->1024 | Whs 32768 | Wls 32768 | Qb bf16 7*NTOT/2]
    float* ws     = (float*)d_ws;
    float* acc    = ws;
    float* coords = ws + 576;
    unsigned short* Whs = (unsigned short*)(ws + 1024);
    unsigned short* Wls = (unsigned short*)(ws + 1024 + 32768);
    unsigned short* Qb  = (unsigned short*)(ws + 1024 + 65536);  // 7 bf16 fields
    float* w      = out;   // working A-output (fp32), updated in place per step

    init_kernel<<<dim3(1), dim3(256), 0, stream>>>(ws);
    wsplit_kernel<<<dim3(8, 16), dim3(64), 0, stream>>>(W, Whs, Wls);

    dim3 ga(64, 8), blk(256);
#define STEPK(K) step_kernel<K><<<ga, blk, 0, stream>>>(v, s0, Whs, Wls, Qb, acc, w);
    STEPK(0) STEPK(1) STEPK(2) STEPK(3) STEPK(4) STEPK(5) STEPK(6) STEPK(7)
#undef STEPK

    expm_kernel<<<dim3(8), dim3(128), 0, stream>>>(acc, coords);
    combine_kernel<<<dim3(256, 8), blk, 0, stream>>>(Qb, v, coords, out);
}

// Round 2
// 541.573 us; speedup vs baseline: 2.5144x; 2.5144x over previous
//
#include <hip/hip_runtime.h>
#include <math.h>

#define Bn   8
#define Cn   256
#define HWn  4096
#define FB   (Cn * HWn)      // 1048576 elems per batch-field
#define NTOT (Bn * FB)       // 8388608 elems per field
#define TEND 1.0
#define EPSK 1e-12f
#define NT   64              // apply N-tile (positions)
#define RS   56              // Pb LDS row stride (bf16) — 112B: 2-way bank alias only
#define WTS  68              // w-tile / tred LDS row stride (floats), padded

typedef float f32x4 __attribute__((ext_vector_type(4)));
typedef short bf16x8 __attribute__((ext_vector_type(8)));

__device__ inline float b2f(unsigned int u) {
    return __uint_as_float(u << 16);
}
__device__ inline unsigned short f2b(float f) {  // RNE
    unsigned u = __float_as_uint(f);
    unsigned r = u + 0x7FFFu + ((u >> 16) & 1u);
    return (unsigned short)(r >> 16);
}

// acc layout (floats, 8 batches each):
//   D[k][j] at acc[(k*8+j)*8 + b];  Nsq[j] at acc[512 + j*8 + b];  coords at acc+576

__global__ void init_kernel(float* __restrict__ p) {
    for (int i = threadIdx.x; i < 1024; i += 256) p[i] = 0.0f;
}

// ---- split W into bf16 hi/lo in MFMA-A staged layout ----
// layout: Whs[((kc*16+mt)*64+lane)*8+j] = bf16 of W[mt*16+(lane&15)][kc*32+(lane>>4)*8+j]
__global__ void wsplit_kernel(const float* __restrict__ W,
                              unsigned short* __restrict__ Whs,
                              unsigned short* __restrict__ Wls) {
    int kc = blockIdx.x, mt = blockIdx.y, l = threadIdx.x;
    int m = mt * 16 + (l & 15);
    int k0 = kc * 32 + (l >> 4) * 8;
#pragma unroll
    for (int j = 0; j < 8; ++j) {
        float wv = W[m * 256 + k0 + j];
        unsigned short h = f2b(wv);
        unsigned short lo = f2b(wv - b2f(h));
        int idx = ((kc * 16 + mt) * 64 + l) * 8 + j;
        Whs[idx] = h; Wls[idx] = lo;
    }
}

// ================= fused Krylov step K (K = 0..7) =================
// phase 1 : x = U_K = w - sum_{j<K} cj_j * basis_j   (basis_0 = v fp32, else Q bf16)
//           -> write Q_{K-1} field (bf16), Nsq[K] atomic, t[s] = colsum(s0*x) (block-local)
//           (K==0: x = v fp32, Nsq[0] = ||v||^2)
// phase 2 : w' = W @ (s0 .* (x - t))  via split-bf16 MFMA   (Z eliminated)
// epilogue: transpose w' through LDS -> coalesced global write + coalesced dots
//           D[K][j] = <basis_j, w'>, j=0..K (atomics)
template <int K>
__global__ __launch_bounds__(256, 3) void step_kernel(
        const float* __restrict__ v, const float* __restrict__ s0,
        const unsigned short* __restrict__ Whs, const unsigned short* __restrict__ Wls,
        unsigned short* __restrict__ Qb, float* __restrict__ acc,
        float* __restrict__ w) {
    // union: phase1/2 use Ph/Pl/tred; epilogue reuses the whole region as wt
    __shared__ __align__(16) char smem_u[34816];        // 34 KB
    short* Ph   = (short*)smem_u;                        // 7168 B
    short* Pl   = (short*)(smem_u + 7168);               // 7168 B
    float* tred = (float*)(smem_u + 14336);              // 16*WTS*4 = 4352 B
    float* wt   = (float*)smem_u;                        // 128*WTS*4 = 34816 B (epilogue)
    __shared__ float ts[NT];
    __shared__ float nred[4];
    __shared__ float dred[4][8];
    const int tid = threadIdx.x;
    const int b = blockIdx.y;
    const int sbase = blockIdx.x * NT;
    const size_t boff = (size_t)b * FB;
    const int lane = tid & 63, wvi = tid >> 6;
    const int mbase = wvi * 64;
    const int cg = tid >> 4;         // 0..15
    const int pos = (tid & 15) * 4;  // 0..60

    // ---- CGS coefficients from previous step's dots ----
    float cj[K > 0 ? K : 1];
    if (K > 0) {
        float mm[K > 0 ? K : 1];
        mm[0] = sqrtf(acc[512 + b]);
#pragma unroll
        for (int j = 1; j < K; ++j) mm[j] = sqrtf(acc[512 + j * 8 + b]) + EPSK * mm[j - 1];
#pragma unroll
        for (int j = 0; j < K; ++j)
            cj[j] = acc[((K - 1) * 8 + j) * 8 + b] / (mm[j] * mm[j]);
    }
    unsigned short* QK = Qb + (size_t)(K > 0 ? K - 1 : 0) * NTOT;

    // ---- phase 1 ----
    float tp[4] = {0.f, 0.f, 0.f, 0.f};
    float np = 0.f;
#pragma unroll 4
    for (int cc = 0; cc < 16; ++cc) {
        int c = cc * 16 + cg;
        size_t off = boff + (size_t)c * HWn + sbase + pos;
        float4 sv = *(const float4*)(s0 + off);
        float se[4] = {sv.x, sv.y, sv.z, sv.w};
        if (K == 0) {
            float4 xv = *(const float4*)(v + off);
            float xe[4] = {xv.x, xv.y, xv.z, xv.w};
#pragma unroll
            for (int i = 0; i < 4; ++i) {
                np = fmaf(xe[i], xe[i], np);
                tp[i] = fmaf(xe[i], se[i], tp[i]);
            }
        } else {
            float4 wv4 = *(const float4*)(w + off);
            float4 vv4 = *(const float4*)(v + off);
            float xe[4];
            xe[0] = fmaf(-cj[0], vv4.x, wv4.x);
            xe[1] = fmaf(-cj[0], vv4.y, wv4.y);
            xe[2] = fmaf(-cj[0], vv4.z, wv4.z);
            xe[3] = fmaf(-cj[0], vv4.w, wv4.w);
#pragma unroll
            for (int j = 1; j < K; ++j) {
                ushort4 u = *(const ushort4*)(Qb + (size_t)(j - 1) * NTOT + off);
                xe[0] = fmaf(-cj[j], b2f(u.x), xe[0]);
                xe[1] = fmaf(-cj[j], b2f(u.y), xe[1]);
                xe[2] = fmaf(-cj[j], b2f(u.z), xe[2]);
                xe[3] = fmaf(-cj[j], b2f(u.w), xe[3]);
            }
            unsigned int h0 = f2b(xe[0]), h1 = f2b(xe[1]);
            unsigned int h2 = f2b(xe[2]), h3 = f2b(xe[3]);
            ushort4 o;
            o.x = (unsigned short)h0; o.y = (unsigned short)h1;
            o.z = (unsigned short)h2; o.w = (unsigned short)h3;
            *(ushort4*)(QK + off) = o;
            float xr[4] = {b2f(h0), b2f(h1), b2f(h2), b2f(h3)};
#pragma unroll
            for (int i = 0; i < 4; ++i) {
                np = fmaf(xr[i], xr[i], np);
                tp[i] = fmaf(xr[i], se[i], tp[i]);
            }
        }
    }
    for (int off2 = 32; off2 > 0; off2 >>= 1) np += __shfl_down(np, off2);
    if (lane == 0) nred[wvi] = np;
    *(float4*)(tred + cg * WTS + pos) = *(float4*)tp;
    __syncthreads();
    if (tid < 64) {
        float s = 0.f;
#pragma unroll
        for (int g = 0; g < 16; ++g) s += tred[g * WTS + tid];
        ts[tid] = s;
    }
    if (tid == 0)
        atomicAdd(&acc[512 + K * 8 + b], nred[0] + nred[1] + nred[2] + nred[3]);
    __syncthreads();

    // ---- phase 2: MFMA over 8 k-chunks ----
    f32x4 ac[4][4];
#pragma unroll
    for (int i = 0; i < 4; ++i)
#pragma unroll
        for (int j = 0; j < 4; ++j) ac[i][j] = (f32x4){0.f, 0.f, 0.f, 0.f};

    for (int kc = 0; kc < 8; ++kc) {
        __syncthreads();  // protect Ph/Pl from previous chunk's reads
#pragma unroll
        for (int ci = 0; ci < 2; ++ci) {
            int cl = ci * 16 + cg;          // 0..31
            int c = kc * 32 + cl;
            size_t off = boff + (size_t)c * HWn + sbase + pos;
            float4 sv = *(const float4*)(s0 + off);
            float se[4] = {sv.x, sv.y, sv.z, sv.w};
            float xr[4];
            if (K == 0) {
                float4 xv = *(const float4*)(v + off);
                xr[0] = xv.x; xr[1] = xv.y; xr[2] = xv.z; xr[3] = xv.w;
            } else {
                ushort4 u = *(const ushort4*)(QK + off);   // just written, L1/L2-hot
                xr[0] = b2f(u.x); xr[1] = b2f(u.y); xr[2] = b2f(u.z); xr[3] = b2f(u.w);
            }
#pragma unroll
            for (int i = 0; i < 4; ++i) {
                float p = se[i] * (xr[i] - ts[pos + i]);
                unsigned short h = f2b(p);
                unsigned short l = f2b(p - b2f(h));
                Ph[(pos + i) * RS + cl] = (short)h;
                Pl[(pos + i) * RS + cl] = (short)l;
            }
        }
        __syncthreads();
        bf16x8 ah[4], al[4], bh[4], bl[4];
#pragma unroll
        for (int rt = 0; rt < 4; ++rt) {
            int mt = (mbase >> 4) + rt;
            ah[rt] = *(const bf16x8*)(Whs + (size_t)kc * 8192 + (mt * 64 + lane) * 8);
            al[rt] = *(const bf16x8*)(Wls + (size_t)kc * 8192 + (mt * 64 + lane) * 8);
        }
#pragma unroll
        for (int ct = 0; ct < 4; ++ct) {
            int n = ct * 16 + (lane & 15);
            int k8 = (lane >> 4) * 8;
            bh[ct] = *(bf16x8*)(Ph + n * RS + k8);
            bl[ct] = *(bf16x8*)(Pl + n * RS + k8);
        }
#pragma unroll
        for (int rt = 0; rt < 4; ++rt)
#pragma unroll
            for (int ct = 0; ct < 4; ++ct) {
                ac[rt][ct] = __builtin_amdgcn_mfma_f32_16x16x32_bf16(ah[rt], bh[ct], ac[rt][ct], 0, 0, 0);
                ac[rt][ct] = __builtin_amdgcn_mfma_f32_16x16x32_bf16(ah[rt], bl[ct], ac[rt][ct], 0, 0, 0);
                ac[rt][ct] = __builtin_amdgcn_mfma_f32_16x16x32_bf16(al[rt], bh[ct], ac[rt][ct], 0, 0, 0);
            }
    }

    // ---- epilogue: LDS transpose -> coalesced w' write + coalesced dots ----
    float dp[K + 1];
#pragma unroll
    for (int j = 0; j <= K; ++j) dp[j] = 0.f;
#pragma unroll
    for (int g = 0; g < 2; ++g) {
        __syncthreads();   // Ph/Pl (aliased by wt) reads done / prev group done
        if ((wvi >> 1) == g) {
            int rl = (wvi & 1) * 64;
#pragma unroll
            for (int rt = 0; rt < 4; ++rt)
#pragma unroll
                for (int ct = 0; ct < 4; ++ct) {
                    int r0 = rl + rt * 16 + (lane >> 4) * 4;
                    int ccol = ct * 16 + (lane & 15);
#pragma unroll
                    for (int reg = 0; reg < 4; ++reg)
                        wt[(r0 + reg) * WTS + ccol] = ac[rt][ct][reg];
                }
        }
        __syncthreads();
        // 8 rounds: 16 rows/round, 16 lanes cover one row (float4 each)
#pragma unroll
        for (int rr = 0; rr < 8; ++rr) {
            int rlocal = rr * 16 + (tid >> 4);
            int rabs = g * 128 + rlocal;
            int col = (tid & 15) * 4;
            const float* src = wt + rlocal * WTS + col;
            float4 wv4 = {src[0], src[1], src[2], src[3]};
            size_t idx = boff + (size_t)rabs * HWn + sbase + col;
            *(float4*)(w + idx) = wv4;
            float4 vv4 = *(const float4*)(v + idx);
            dp[0] = fmaf(wv4.x, vv4.x, dp[0]);
            dp[0] = fmaf(wv4.y, vv4.y, dp[0]);
            dp[0] = fmaf(wv4.z, vv4.z, dp[0]);
            dp[0] = fmaf(wv4.w, vv4.w, dp[0]);
#pragma unroll
            for (int j = 1; j <= K; ++j) {
                ushort4 u = *(const ushort4*)(Qb + (size_t)(j - 1) * NTOT + idx);
                dp[j] = fmaf(wv4.x, b2f(u.x), dp[j]);
                dp[j] = fmaf(wv4.y, b2f(u.y), dp[j]);
                dp[j] = fmaf(wv4.z, b2f(u.z), dp[j]);
                dp[j] = fmaf(wv4.w, b2f(u.w), dp[j]);
            }
        }
    }
#pragma unroll
    for (int j = 0; j <= K; ++j) {
        float q = dp[j];
        for (int off2 = 32; off2 > 0; off2 >>= 1) q += __shfl_down(q, off2);
        if (lane == 0) dred[wvi][j] = q;
    }
    __syncthreads();
    if (tid <= K)
        atomicAdd(&acc[(K * 8 + tid) * 8 + b],
                  dred[0][tid] + dred[1][tid] + dred[2][tid] + dred[3][tid]);
}

// ---------------- expm of 9x9 per batch (fp64); emits combine coeffs ----------
__global__ __launch_bounds__(128) void expm_kernel(const float* __restrict__ acc,
                                                   float* __restrict__ coordsOut) {
    __shared__ double Am[81], Pm[81], Tm[81];
    __shared__ double ssc;
    __shared__ int sn;
    const int b = blockIdx.x;
    const int t = threadIdx.x;
    const int r = t / 9, c = t % 9;
    double m[8];
    m[0] = sqrt((double)acc[512 + b]);
    for (int j = 1; j < 8; ++j) m[j] = sqrt((double)acc[512 + j * 8 + b]) + 1e-12 * m[j - 1];
    if (t < 81) {
        double val = 0.0;
        if (r < 8 && c < 8) {
            if (r <= c) val = TEND * (double)acc[(c * 8 + r) * 8 + b] / (m[r] * m[c]);
            else if (r == c + 1) val = TEND * sqrt((double)acc[512 + r * 8 + b]) / m[c];
        }
        if (r == 0 && c == 8) val = TEND;
        Am[t] = val;
    }
    __syncthreads();
    if (t == 0) {
        double mx = 0.0;
        for (int rr = 0; rr < 9; ++rr) {
            double s = 0.0;
            for (int cc = 0; cc < 9; ++cc) s += fabs(Am[rr * 9 + cc]);
            if (s > mx) mx = s;
        }
        int n = 0;
        while (mx > 0.25 && n < 48) { mx *= 0.5; ++n; }
        double sc = 1.0;
        for (int ii = 0; ii < n; ++ii) sc *= 0.5;
        sn = n; ssc = sc;
    }
    __syncthreads();
    if (t < 81) Am[t] *= ssc;
    __syncthreads();
    if (t < 81) Pm[t] = (r == c) ? 1.0 : 0.0;
    __syncthreads();
    for (int i = 20; i >= 1; --i) {
        if (t < 81) {
            double s = 0.0;
            for (int k = 0; k < 9; ++k) s += Am[r * 9 + k] * Pm[k * 9 + c];
            Tm[t] = ((r == c) ? 1.0 : 0.0) + s / (double)i;
        }
        __syncthreads();
        if (t < 81) Pm[t] = Tm[t];
        __syncthreads();
    }
    int n = sn;
    for (int q = 0; q < n; ++q) {
        if (t < 81) {
            double s = 0.0;
            for (int k = 0; k < 9; ++k) s += Pm[r * 9 + k] * Pm[k * 9 + c];
            Tm[t] = s;
        }
        __syncthreads();
        if (t < 81) Pm[t] = Tm[t];
        __syncthreads();
    }
    if (t < 8) coordsOut[b * 8 + t] = (float)(Pm[t * 9 + 8] * m[0] / m[t]);
}

__device__ inline void unp8(uint4 u, float* f) {
    f[0] = b2f(u.x & 0xFFFFu); f[1] = b2f(u.x >> 16);
    f[2] = b2f(u.y & 0xFFFFu); f[3] = b2f(u.y >> 16);
    f[4] = b2f(u.z & 0xFFFFu); f[5] = b2f(u.z >> 16);
    f[6] = b2f(u.w & 0xFFFFu); f[7] = b2f(u.w >> 16);
}

// ------ out = coeff_0*v + sum_{j=1..7} coeff_j * U_j (bf16) ------
__global__ __launch_bounds__(256) void combine_kernel(const unsigned short* __restrict__ Qb,
                                                      const float* __restrict__ v,
                                                      const float* __restrict__ coords,
                                                      float* __restrict__ out) {
    int b = blockIdx.y;
    const size_t boff = (size_t)b * FB;
    float cf[8];
#pragma unroll
    for (int j = 0; j < 8; ++j) cf[j] = coords[b * 8 + j];
    const float4* vv = (const float4*)(v + boff);
    const uint4* uv[8];
#pragma unroll
    for (int j = 1; j < 8; ++j)
        uv[j] = (const uint4*)(Qb + (size_t)(j - 1) * NTOT + boff);
    int i = blockIdx.x * 256 + threadIdx.x;
    float4* ov = (float4*)(out + boff);
#pragma unroll
    for (int r = 0; r < 2; ++r) {
        int idx = i + r * 65536;
        float4 v0 = vv[2 * idx], v1 = vv[2 * idx + 1];
        float a[8] = {cf[0] * v0.x, cf[0] * v0.y, cf[0] * v0.z, cf[0] * v0.w,
                      cf[0] * v1.x, cf[0] * v1.y, cf[0] * v1.z, cf[0] * v1.w};
#pragma unroll
        for (int j = 1; j < 8; ++j) {
            uint4 u = uv[j][idx];
            float ue[8]; unp8(u, ue);
#pragma unroll
            for (int e = 0; e < 8; ++e) a[e] = fmaf(cf[j], ue[e], a[e]);
        }
        float4 o0 = {a[0], a[1], a[2], a[3]};
        float4 o1 = {a[4], a[5], a[6], a[7]};
        ov[2 * idx] = o0; ov[2 * idx + 1] = o1;
    }
}

extern "C" void kernel_launch(void* const* d_in, const int* in_sizes, int n_in,
                              void* d_out, int out_size, void* d_ws, size_t ws_size,
                              hipStream_t stream) {
    const float* s0 = (const float*)d_in[0];
    const float* v  = (const float*)d_in[1];
    const float* W  = (const float*)d_in[2];
    float* out = (float*)d_out;

    // ws (floats): [acc 576 | coords 64 | pad->1024 | Whs 32768 | Wls 32768 | Qb bf16 7*NTOT/2]
    float* ws     = (float*)d_ws;
    float* acc    = ws;
    float* coords = ws + 576;
    unsigned short* Whs = (unsigned short*)(ws + 1024);
    unsigned short* Wls = (unsigned short*)(ws + 1024 + 32768);
    unsigned short* Qb  = (unsigned short*)(ws + 1024 + 65536);  // 7 bf16 fields
    float* w      = out;   // working A-output (fp32), updated in place per step

    init_kernel<<<dim3(1), dim3(256), 0, stream>>>(ws);
    wsplit_kernel<<<dim3(8, 16), dim3(64), 0, stream>>>(W, Whs, Wls);

    dim3 ga(64, 8), blk(256);
#define STEPK(K) step_kernel<K><<<ga, blk, 0, stream>>>(v, s0, Whs, Wls, Qb, acc, w);
    STEPK(0) STEPK(1) STEPK(2) STEPK(3) STEPK(4) STEPK(5) STEPK(6) STEPK(7)
#undef STEPK

    expm_kernel<<<dim3(8), dim3(128), 0, stream>>>(acc, coords);
    combine_kernel<<<dim3(256, 8), blk, 0, stream>>>(Qb, v, coords, out);
}